// Round 4
// baseline (100.931 us; speedup 1.0000x reference)
//
#include <hip/hip_runtime.h>
#include <stdint.h>

// DigitCaps with O=1: routing softmax over one out-capsule is identity, so
// the reference reduces to
//   s[b,v]  = sum_{i,d} W[i,v,d] * x[b,i,d]        (M=32, N=512, K=32768 GEMM)
//   out     = s * sqrt(sq)/(1+sq),  sq = sum_v s^2  (per-b squash)
// Both tuple outputs (t, outputs) are identical [32,1,512] tensors.
//
// R20: KB 64 -> 32. Each mfma block now covers 1024 k in TWO staged passes
// over the same 64 KB LDS (stage 512k -> MFMA -> barrier -> stage next 512k
// -> MFMA), acc carried in registers. Halves partial_h (2->1 MB round-trip)
// and halves caps_finish's per-thread loads. Pass-1 W loads issue right
// after pass-0 MFMAs so they fly under the pass-1 staging barrier (<=8
// VMEM dests in flight per wave, same as R19).
// R19: x staged through LDS in fragment order (coalesced 512-B row
// segments, hi/lo split in-register, XOR-swizzled writes).

#define NB 32
#define NI 4096
#define NV 512
#define ND 8
#define NK 32768            // K = NI*ND
#define KB 32               // k-blocks (partial slices)
#define KSB (NK / KB)       // 1024 k per block (2 passes of 512)

typedef __fp16 f16x8 __attribute__((ext_vector_type(8)));
typedef __fp16 f16x4 __attribute__((ext_vector_type(4)));
typedef __fp16 f16x2 __attribute__((ext_vector_type(2)));
typedef float  f32x16 __attribute__((ext_vector_type(16)));

// ---------------------------------------------------------------------------
// Kernel 1: partial_h[kb][b][v] (f16) = sum over 1024-k slice of x*W.
// Grid: kb(32) x vg(16) = 512 blocks of 1024 threads (16 waves).
// Per pass p (0,1): stage x[32 rows][512 k] -> hi/lo f16 fragment-order LDS
// (swizzled), then per-wave ds_read_b128 frags + 4 W float4 + 4 MFMAs.
// Epilogue: 16-wave LDS k-reduce (reusing the stage buffer) -> f16 tile.
// ---------------------------------------------------------------------------
__global__ __launch_bounds__(1024) void caps_mfma(
    const float* __restrict__ W, const float* __restrict__ x,
    __fp16* __restrict__ partial_h)
{
    const int t    = threadIdx.x;
    const int lane = t & 63;
    const int wave = t >> 6;       // 0..15
    const int half = lane >> 5;    // 0/1: which 8-k group of a 16-k step
    const int ln32 = lane & 31;

    const int kb = blockIdx.x & (KB - 1);
    const int vg = blockIdx.x >> 5;
    const int v0 = vg * 32;

    // local (within a 512-k pass) k-groups for this wave's two ksteps
    const int g0l = wave * 4 + half;     // 0..63
    const int g1l = g0l + 2;

    // fragment-read LDS offsets (same layout both passes)
    const int e0 = g0l * 256 + ((ln32 * 8) ^ ((g0l & 7) << 3));
    const int e1 = g1l * 256 + ((ln32 * 8) ^ ((g1l & 7) << 3));

    __shared__ __align__(16) __fp16 xs[2 * 16384];   // hi plane, lo plane: 64 KB

    const int r = t >> 5;              // x row 0..31
    const int c = t & 31;

    f32x16 acc;
#pragma unroll
    for (int rr = 0; rr < 16; ++rr) acc[rr] = 0.0f;

    // ---- pass-0 W loads issued first (hide under pass-0 staging) ----
    const int gW0 = kb * (KSB / 8) + g0l;     // global k-group, pass 0
    const float4* wq0 = (const float4*)(W + ((size_t)gW0 * NV + v0 + ln32) * ND);
    const float4* wq1 = (const float4*)(W + ((size_t)(gW0 + 2) * NV + v0 + ln32) * ND);
    float4 w00 = wq0[0];
    float4 w01 = wq0[1];
    float4 w10 = wq1[0];
    float4 w11 = wq1[1];

#pragma unroll
    for (int p = 0; p < 2; ++p) {
        // ---- stage x slice [32 rows][512 k] -> fragment-order LDS ----
        // Plane layout (f16 elems): [gp 0..63][slot], slot = 32 rows x 8 k,
        // swizzled: eoff = gp*256 + ((r*8 + part*4) ^ ((gp&7)<<3)).
        const float* xrow = x + (size_t)r * NK + (size_t)kb * KSB + p * 512;
#pragma unroll
        for (int j = 0; j < 4; ++j) {
            const int kl = (c + 32 * j) * 4;          // k offset in pass, step 4
            const float4 f = *(const float4*)(xrow + kl);   // coalesced 512-B segs
            const int gp   = kl >> 3;                 // local k-group 0..63
            const int part = (kl >> 2) & 1;           // low/high half of group
            const f16x2 hA = __builtin_amdgcn_cvt_pkrtz(f.x, f.y);
            const f16x2 hB = __builtin_amdgcn_cvt_pkrtz(f.z, f.w);
            const f16x2 lA = __builtin_amdgcn_cvt_pkrtz(f.x - (float)hA.x, f.y - (float)hA.y);
            const f16x2 lB = __builtin_amdgcn_cvt_pkrtz(f.z - (float)hB.x, f.w - (float)hB.y);
            const int eoff = gp * 256 + ((r * 8 + part * 4) ^ ((gp & 7) << 3));
            *(f16x4*)(xs + eoff)         = (f16x4){hA.x, hA.y, hB.x, hB.y};
            *(f16x4*)(xs + 16384 + eoff) = (f16x4){lA.x, lA.y, lB.x, lB.y};
        }
        __syncthreads();

        // ---- fragment reads + MFMA ----
        const f16x8 a0h = *(const f16x8*)(xs + e0);
        const f16x8 a0l = *(const f16x8*)(xs + 16384 + e0);
        const f16x8 a1h = *(const f16x8*)(xs + e1);
        const f16x8 a1l = *(const f16x8*)(xs + 16384 + e1);

        // W -> f16 (single plane; |W|~0.01 so rtz rel err 2^-11 is enough)
        const f16x2 p01 = __builtin_amdgcn_cvt_pkrtz(w00.x, w00.y);
        const f16x2 p23 = __builtin_amdgcn_cvt_pkrtz(w00.z, w00.w);
        const f16x2 p45 = __builtin_amdgcn_cvt_pkrtz(w01.x, w01.y);
        const f16x2 p67 = __builtin_amdgcn_cvt_pkrtz(w01.z, w01.w);
        const f16x8 b0 = {p01.x, p01.y, p23.x, p23.y, p45.x, p45.y, p67.x, p67.y};
        const f16x2 q01 = __builtin_amdgcn_cvt_pkrtz(w10.x, w10.y);
        const f16x2 q23 = __builtin_amdgcn_cvt_pkrtz(w10.z, w10.w);
        const f16x2 q45 = __builtin_amdgcn_cvt_pkrtz(w11.x, w11.y);
        const f16x2 q67 = __builtin_amdgcn_cvt_pkrtz(w11.z, w11.w);
        const f16x8 b1 = {q01.x, q01.y, q23.x, q23.y, q45.x, q45.y, q67.x, q67.y};

        acc = __builtin_amdgcn_mfma_f32_32x32x16_f16(a0h, b0, acc, 0, 0, 0);
        acc = __builtin_amdgcn_mfma_f32_32x32x16_f16(a0l, b0, acc, 0, 0, 0);
        acc = __builtin_amdgcn_mfma_f32_32x32x16_f16(a1h, b1, acc, 0, 0, 0);
        acc = __builtin_amdgcn_mfma_f32_32x32x16_f16(a1l, b1, acc, 0, 0, 0);

        if (p == 0) {
            // issue pass-1 W loads; they fly under the pass-1 staging
            const int gW1 = gW0 + 64;
            const float4* wr0 = (const float4*)(W + ((size_t)gW1 * NV + v0 + ln32) * ND);
            const float4* wr1 = (const float4*)(W + ((size_t)(gW1 + 2) * NV + v0 + ln32) * ND);
            w00 = wr0[0];
            w01 = wr0[1];
            w10 = wr1[0];
            w11 = wr1[1];
        }
        __syncthreads();   // frag reads done -> LDS reusable (stage p1 / reduce)
    }

    // ---- epilogue: 16-wave k-reduce, reusing the stage LDS (64 KB) ----
    float* red = (float*)xs;           // 16 * 1024 floats
#pragma unroll
    for (int rr = 0; rr < 16; ++rr)
        red[wave * 1024 + rr * 64 + lane] = acc[rr];
    __syncthreads();

    float val = 0.0f;
#pragma unroll
    for (int w = 0; w < 16; ++w)       // 16 independent LDS reads
        val += red[w * 1024 + t];

    const int rg = t >> 6;
    const int ln = t & 63;
    // C/D layout (m74/m101): col = lane&31 (v), row = (reg&3)+8*(reg>>2)+4*(lane>>5) (b)
    const int row = (rg & 3) + 8 * (rg >> 2) + 4 * (ln >> 5);
    const int col = ln & 31;
    partial_h[((size_t)kb * NB + row) * NV + v0 + col] = (__fp16)val;
}

// ---------------------------------------------------------------------------
// Kernel 2: reduce KB f16 slices + squash + write both outputs.
// Grid: 32 blocks (one per b) x 1024 threads. Thread t: v = t&511,
// kb-half = t>>9 (16 slices each) -> 2-way MLP; LDS combine; squash.
// ---------------------------------------------------------------------------
__global__ __launch_bounds__(1024) void caps_finish(
    const __fp16* __restrict__ partial_h, float* __restrict__ out)
{
    const int t = threadIdx.x;
    const int v = t & 511;
    const int h = t >> 9;              // 0/1: which half of the kb range
    const int b = blockIdx.x;

    float s = 0.0f;
#pragma unroll
    for (int g = 0; g < KB / 2; ++g)   // 16 independent coalesced loads
        s += (float)partial_h[((size_t)(h * (KB / 2) + g) * NB + b) * NV + v];

    __shared__ float sv[1024];
    sv[t] = s;
    __syncthreads();

    float sq = 0.0f;
    float stot = 0.0f;
    if (t < 512) {
        stot = sv[t] + sv[t + 512];
        sq = stot * stot;
    }
#pragma unroll
    for (int off = 32; off > 0; off >>= 1)
        sq += __shfl_xor(sq, off, 64);

    __shared__ float red[16];
    if ((t & 63) == 0) red[t >> 6] = sq;
    __syncthreads();
    if (t < 512) {
        float tot = 0.0f;
#pragma unroll
        for (int wv = 0; wv < 16; ++wv) tot += red[wv];  // waves 8..15 wrote 0

        // squash factor: sq/((1+sq)*sqrt(sq)) == sqrt(sq)/(1+sq)
        const float factor = sqrtf(tot) / (1.0f + tot);
        const float r = stot * factor;

        out[(size_t)b * NV + v]           = r;  // output 0: t       [B,1,V]
        out[NB * NV + (size_t)b * NV + v] = r;  // output 1: outputs [B,O,V]
    }
}

extern "C" void kernel_launch(void* const* d_in, const int* in_sizes, int n_in,
                              void* d_out, int out_size, void* d_ws, size_t ws_size,
                              hipStream_t stream) {
    const float* x = (const float*)d_in[0];   // [32, 4096, 8]
    const float* W = (const float*)d_in[1];   // [1, 4096, 512, 8]
    float* out     = (float*)d_out;           // 2 x [32,1,512] concatenated

    __fp16* partialh = (__fp16*)d_ws;         // 1 MB (f16, KB=32)

    caps_mfma<<<KB * 16, 1024, 0, stream>>>(W, x, partialh);
    caps_finish<<<NB, 1024, 0, stream>>>(partialh, out);
}